// Round 7
// baseline (340.509 us; speedup 1.0000x reference)
//
#include <hip/hip_runtime.h>
#include <math.h>

// Problem constants
constexpr int Bn = 512;
constexpr int Tn = 512;
constexpr int Dn = 128;
constexpr int Hn = 128;

// ---------------- K1: u[b] = Wx * (Wt^T * last_visit[b]) ----------------
__global__ __launch_bounds__(128)
void compute_u_kernel(const float* __restrict__ input,   // [B,T,D]
                      const int*   __restrict__ mask,    // [B,T]
                      const float* __restrict__ Wt,      // [D,H]
                      const float* __restrict__ Wx,      // [D,H]
                      float* __restrict__ ws_u)          // [B,D]
{
    const int b   = blockIdx.x;
    const int tid = threadIdx.x;            // 0..127
    const float* __restrict__ inb = input + (size_t)b * Tn * Dn;

    __shared__ float lvs[Dn];
    __shared__ float qs[Hn];
    __shared__ int   ired[2];

    // mask sum (512 ints by 128 threads, int4 each)
    const int4 m4 = ((const int4*)(mask + (size_t)b * Tn))[tid];
    int ms = m4.x + m4.y + m4.z + m4.w;
    #pragma unroll
    for (int off = 32; off > 0; off >>= 1) ms += __shfl_down(ms, off, 64);
    if ((tid & 63) == 0) ired[tid >> 6] = ms;
    __syncthreads();
    const int last_idx = ired[0] + ired[1] - 1;

    lvs[tid] = inb[(size_t)last_idx * Dn + tid];
    __syncthreads();

    float q = 0.f;
    #pragma unroll 16
    for (int d = 0; d < Dn; ++d) q = fmaf(lvs[d], Wt[d * Hn + tid], q);
    qs[tid] = q;
    __syncthreads();

    float u = 0.f;
    const float* wxr = Wx + tid * Hn;
    #pragma unroll 16
    for (int h = 0; h < Hn; ++h) u = fmaf(wxr[h], qs[h], u);
    ws_u[b * Dn + tid] = u;
}

// ---------------- K2: half-batch streaming + split-K finish ----------------
constexpr int NTS   = 512;           // threads per block
constexpr int HROWS = Tn / 2;        // 256 rows per block
constexpr int SWEEPS = HROWS / 32;   // 8 sweeps of 32 rows

__global__ __launch_bounds__(NTS, 6)   // VGPR cap ~84 -> >=3 blocks/CU (24+ waves/CU)
void attn_stream_kernel(const float* __restrict__ input,   // [B,T,D]
                        const int*   __restrict__ mask,    // [B,T]
                        const float* __restrict__ ws_u,    // [B,D]
                        const float* __restrict__ rate,    // [1]
                        float* __restrict__ vpart,         // [2B, D]
                        float* __restrict__ lpart,         // [2B]
                        int*   __restrict__ cnt,           // [B], zeroed per call
                        float* __restrict__ out_v,         // [B,D]
                        float* __restrict__ out_a)         // [B,T]
{
    const int j    = blockIdx.x;
    const int b    = j >> 1;
    const int half = j & 1;
    const int tid  = threadIdx.x;
    const int lane = tid & 63;
    const int wid  = tid >> 6;
    const int seg  = tid & 15;     // 16 lanes per row: floats seg*8..seg*8+7
    const int rg   = tid >> 4;     // row group 0..31
    const int rbase = half * HROWS;
    const float4* __restrict__ in4 = (const float4*)(input + (size_t)b * Tn * Dn);

    __shared__ int   msk[HROWS];       // 1 KB
    __shared__ float vp[32 * 132];     // 16.9 KB v partials
    __shared__ float redl[NTS / 64];
    __shared__ int   sold;

    if (tid < HROWS) msk[tid] = mask[(size_t)b * Tn + rbase + tid];
    const float4 u4a = ((const float4*)(ws_u + b * Dn))[seg * 2];
    const float4 u4b = ((const float4*)(ws_u + b * Dn))[seg * 2 + 1];
    const float srate = 1.f / (1.f + __expf(-rate[0]));
    __syncthreads();

    // e = relu(sig/den) is bounded in [0, ~1.45] (den >= sigmoid(0.8)*log(2.72) ~ 0.69),
    // so exp(e) <= 4.3: softmax needs no max subtraction.
    float4 v0 = make_float4(0.f, 0.f, 0.f, 0.f);
    float4 v1 = make_float4(0.f, 0.f, 0.f, 0.f);
    float  lsum = 0.f;

    #pragma unroll 4
    for (int s = 0; s < SWEEPS; ++s) {
        const int rl  = s * 32 + rg;       // local row 0..255
        const int row = rbase + rl;        // global t
        const float4 x0 = in4[row * 32 + seg * 2];
        const float4 x1 = in4[row * 32 + seg * 2 + 1];
        float dot = x0.x * u4a.x + x0.y * u4a.y + x0.z * u4a.z + x0.w * u4a.w;
        dot = fmaf(x1.x, u4b.x, dot);
        dot = fmaf(x1.y, u4b.y, dot);
        dot = fmaf(x1.z, u4b.z, dot);
        dot = fmaf(x1.w, u4b.w, dot);
        #pragma unroll
        for (int mm = 1; mm < 16; mm <<= 1) dot += __shfl_xor(dot, mm, 64);
        const float sig = 1.f / (1.f + __expf(-dot));
        const float den = srate * (__logf(2.72f + (1.f - sig)) * (float)(Tn - row));
        const float e   = fmaxf(sig / den, 0.f);
        const float p   = msk[rl] ? __expf(e) : 0.f;
        v0.x = fmaf(p, x0.x, v0.x);
        v0.y = fmaf(p, x0.y, v0.y);
        v0.z = fmaf(p, x0.z, v0.z);
        v0.w = fmaf(p, x0.w, v0.w);
        v1.x = fmaf(p, x1.x, v1.x);
        v1.y = fmaf(p, x1.y, v1.y);
        v1.z = fmaf(p, x1.z, v1.z);
        v1.w = fmaf(p, x1.w, v1.w);
        if (seg == 0) { out_a[(size_t)b * Tn + row] = p; lsum += p; }
    }

    // stash v partials (16B-aligned: rg*132 + seg*8)
    {
        float* vr = vp + rg * 132 + seg * 8;
        ((float4*)vr)[0] = v0;
        ((float4*)vr)[1] = v1;
    }
    float ls = lsum;
    #pragma unroll
    for (int off = 32; off > 0; off >>= 1) ls += __shfl_down(ls, off, 64);
    if (lane == 0) redl[wid] = ls;
    __syncthreads();   // vp + redl visible

    if (tid < Dn) {
        float s = 0.f;
        #pragma unroll
        for (int r = 0; r < 32; ++r) s += vp[r * 132 + tid];
        vpart[(size_t)j * Dn + tid] = s;
    }
    if (tid == 0) {
        float l = 0.f;
        #pragma unroll
        for (int w = 0; w < NTS / 64; ++w) l += redl[w];
        lpart[j] = l;
    }

    // ---- split-K finish: last arriver combines both halves ----
    __threadfence();                       // release our vpart/lpart/out_a stores
    __syncthreads();
    if (tid == 0) sold = atomicAdd(&cnt[b], 1);
    __syncthreads();
    if (sold == 1) {
        __threadfence();                   // acquire the other half's stores
        const float l    = lpart[2 * b] + lpart[2 * b + 1];
        const float invl = 1.f / l;
        if (tid < Dn)
            out_v[(size_t)b * Dn + tid] =
                (vpart[(size_t)(2 * b) * Dn + tid] + vpart[(size_t)(2 * b + 1) * Dn + tid]) * invl;
        out_a[(size_t)b * Tn + tid] *= invl;
    }
}

extern "C" void kernel_launch(void* const* d_in, const int* in_sizes, int n_in,
                              void* d_out, int out_size, void* d_ws, size_t ws_size,
                              hipStream_t stream) {
    const float* input = (const float*)d_in[0];   // [B,T,D]
    const int*   mask  = (const int*)d_in[1];     // [B,T]
    const float* Wt    = (const float*)d_in[2];   // [D,H]
    const float* Wx    = (const float*)d_in[3];   // [D,H]
    const float* rate  = (const float*)d_in[4];   // [1]

    float* out   = (float*)d_out;
    float* out_v = out;                 // [B,D]  (return order: v, a)
    float* out_a = out + Bn * Dn;       // [B,T]

    float* ws_u  = (float*)d_ws;                  // [B,D]
    float* vpart = ws_u + (size_t)Bn * Dn;        // [2B,D]
    float* lpart = vpart + (size_t)2 * Bn * Dn;   // [2B]
    int*   cnt   = (int*)(lpart + 2 * Bn);        // [B]

    hipMemsetAsync(cnt, 0, Bn * sizeof(int), stream);
    compute_u_kernel<<<Bn, 128, 0, stream>>>(input, mask, Wt, Wx, ws_u);
    attn_stream_kernel<<<2 * Bn, NTS, 0, stream>>>(input, mask, ws_u, rate,
                                                   vpart, lpart, cnt, out_v, out_a);
}

// Round 8
// 70.859 us; speedup vs baseline: 4.8055x; 4.8055x over previous
//
#include <hip/hip_runtime.h>
#include <math.h>

// Problem constants
constexpr int Bn = 512;
constexpr int Tn = 512;
constexpr int Dn = 128;
constexpr int Hn = 128;
constexpr int NT = 1024;      // threads per block (one block per batch)
constexpr int NW = NT / 64;   // 16 waves
constexpr int RGS = NT / 16;  // 64 row groups (16 lanes per row)
constexpr int SWEEPS = Tn / RGS;  // 8 sweeps

__global__ __launch_bounds__(NT, 8)   // 8 waves/SIMD -> 2 blocks/CU -> 32 waves/CU (VGPR<=64)
void single_attn_fused2(const float* __restrict__ input,   // [B,T,D]
                        const int*   __restrict__ mask,    // [B,T]
                        const float* __restrict__ Wt,      // [D,H]
                        const float* __restrict__ Wx,      // [D,H]
                        const float* __restrict__ rate,    // [1]
                        float* __restrict__ out_v,         // [B,D]
                        float* __restrict__ out_a)         // [B,T]
{
    const int b    = blockIdx.x;
    const int tid  = threadIdx.x;
    const int lane = tid & 63;
    const int wid  = tid >> 6;
    const int seg  = tid & 15;     // 16 lanes per row; floats seg*8..seg*8+7
    const int rg   = tid >> 4;     // row group 0..63
    const float* __restrict__ inb = input + (size_t)b * Tn * Dn;
    const float4* __restrict__ in4 = (const float4*)inb;

    __shared__ float ps[Tn];            // 2 KB unnormalized weights
    __shared__ int   msk[Tn];           // 2 KB
    __shared__ float lv[Dn];
    __shared__ float qs[Hn];
    __shared__ float us[Dn];
    __shared__ float redl[NW];
    __shared__ int   ired[NW];
    __shared__ float vp[RGS * 132];     // 33.8 KB v partials (stride 132 avoids bank alignment)

    // ---- prologue: last_idx, lv, q = lv@Wt, u = Wx@q ----
    int mv = 0;
    if (tid < Tn) { mv = mask[(size_t)b * Tn + tid]; msk[tid] = mv; }
    {
        int ms = mv;
        #pragma unroll
        for (int off = 32; off > 0; off >>= 1) ms += __shfl_down(ms, off, 64);
        if (lane == 0) ired[wid] = ms;
    }
    __syncthreads();
    int last_idx;
    {
        int s = 0;
        #pragma unroll
        for (int w = 0; w < NW; ++w) s += ired[w];
        last_idx = s - 1;
    }
    if (tid < Dn) lv[tid] = inb[(size_t)last_idx * Dn + tid];
    __syncthreads();
    if (tid < Hn) {
        float a0 = 0.f, a1 = 0.f;
        #pragma unroll 16
        for (int d0 = 0; d0 < Dn; d0 += 2) {
            a0 = fmaf(lv[d0],     Wt[d0 * Hn + tid],       a0);
            a1 = fmaf(lv[d0 + 1], Wt[(d0 + 1) * Hn + tid], a1);
        }
        qs[tid] = a0 + a1;
    }
    __syncthreads();
    if (tid < Dn) {
        float a0 = 0.f, a1 = 0.f;
        const float* wxr = Wx + tid * Hn;
        #pragma unroll 16
        for (int h = 0; h < Hn; h += 2) {
            a0 = fmaf(wxr[h],     qs[h],     a0);
            a1 = fmaf(wxr[h + 1], qs[h + 1], a1);
        }
        us[tid] = a0 + a1;
    }
    __syncthreads();

    const float srate = 1.f / (1.f + __expf(-rate[0]));
    const float4 u4a = ((const float4*)us)[seg * 2];
    const float4 u4b = ((const float4*)us)[seg * 2 + 1];

    // ---- fused streaming pass: dot -> p -> weighted accumulate, input read ONCE ----
    // e = relu(sig/den) in [0, ~1.45] (den >= sigmoid(0.8)*log(2.72) ~= 0.69),
    // so exp(e) <= 4.3: softmax needs no max subtraction.
    float4 v0 = make_float4(0.f, 0.f, 0.f, 0.f);
    float4 v1 = make_float4(0.f, 0.f, 0.f, 0.f);
    float  lsum = 0.f;

    #pragma unroll
    for (int it = 0; it < SWEEPS; ++it) {
        const int row = it * RGS + rg;             // == t
        const float4 x0 = in4[row * 32 + seg * 2];
        const float4 x1 = in4[row * 32 + seg * 2 + 1];
        float dot = x0.x * u4a.x + x0.y * u4a.y + x0.z * u4a.z + x0.w * u4a.w;
        dot = fmaf(x1.x, u4b.x, dot);
        dot = fmaf(x1.y, u4b.y, dot);
        dot = fmaf(x1.z, u4b.z, dot);
        dot = fmaf(x1.w, u4b.w, dot);
        #pragma unroll
        for (int mm = 1; mm < 16; mm <<= 1) dot += __shfl_xor(dot, mm, 64);
        const float sig = 1.f / (1.f + __expf(-dot));
        const float den = srate * (__logf(2.72f + (1.f - sig)) * (float)(Tn - row));
        const float e   = fmaxf(sig / den, 0.f);
        const float p   = msk[row] ? __expf(e) : 0.f;
        v0.x = fmaf(p, x0.x, v0.x);
        v0.y = fmaf(p, x0.y, v0.y);
        v0.z = fmaf(p, x0.z, v0.z);
        v0.w = fmaf(p, x0.w, v0.w);
        v1.x = fmaf(p, x1.x, v1.x);
        v1.y = fmaf(p, x1.y, v1.y);
        v1.z = fmaf(p, x1.z, v1.z);
        v1.w = fmaf(p, x1.w, v1.w);
        if (seg == 0) { ps[row] = p; lsum += p; }
    }

    // stash v partials (16B-aligned: rg*132 + seg*8)
    {
        float* vr = vp + rg * 132 + seg * 8;
        ((float4*)vr)[0] = v0;
        ((float4*)vr)[1] = v1;
    }
    // block-reduce l (nonzero only on seg==0 lanes)
    float ls = lsum;
    #pragma unroll
    for (int off = 32; off > 0; off >>= 1) ls += __shfl_down(ls, off, 64);
    if (lane == 0) redl[wid] = ls;
    __syncthreads();   // vp + ps + redl visible

    float l = 0.f;
    #pragma unroll
    for (int w = 0; w < NW; ++w) l += redl[w];
    const float inv_l = 1.f / l;

    if (tid < Tn) out_a[(size_t)b * Tn + tid] = ps[tid] * inv_l;

    if (tid < Dn) {
        float s = 0.f;
        #pragma unroll
        for (int r = 0; r < RGS; ++r) s += vp[r * 132 + tid];
        out_v[(size_t)b * Dn + tid] = s * inv_l;
    }
}

extern "C" void kernel_launch(void* const* d_in, const int* in_sizes, int n_in,
                              void* d_out, int out_size, void* d_ws, size_t ws_size,
                              hipStream_t stream) {
    const float* input = (const float*)d_in[0];   // [B,T,D]
    const int*   mask  = (const int*)d_in[1];     // [B,T]
    const float* Wt    = (const float*)d_in[2];   // [D,H]
    const float* Wx    = (const float*)d_in[3];   // [D,H]
    const float* rate  = (const float*)d_in[4];   // [1]

    float* out   = (float*)d_out;
    float* out_v = out;                 // [B,D]  (return order: v, a)
    float* out_a = out + Bn * Dn;       // [B,T]

    single_attn_fused2<<<Bn, NT, 0, stream>>>(input, mask, Wt, Wx, rate, out_v, out_a);
}

// Round 9
// 32.385 us; speedup vs baseline: 10.5144x; 2.1880x over previous
//
#include <hip/hip_runtime.h>
#include <math.h>

// Problem constants
constexpr int Bn = 512;
constexpr int Tn = 512;
constexpr int Dn = 128;
constexpr int Hn = 128;
constexpr int NT = 512;       // threads per block (one block per batch)
constexpr int NW = NT / 64;   // 8 waves

// Sum across the 16-lane row group via DPP row rotations (pure VALU, no LDS).
// After ror:1,2,4,8 accumulation every lane in the 16-group holds the full sum.
__device__ __forceinline__ float rowsum16(float x) {
    int v;
    v = __float_as_int(x);
    x += __int_as_float(__builtin_amdgcn_update_dpp(0, v, 0x121, 0xF, 0xF, true)); // row_ror:1
    v = __float_as_int(x);
    x += __int_as_float(__builtin_amdgcn_update_dpp(0, v, 0x122, 0xF, 0xF, true)); // row_ror:2
    v = __float_as_int(x);
    x += __int_as_float(__builtin_amdgcn_update_dpp(0, v, 0x124, 0xF, 0xF, true)); // row_ror:4
    v = __float_as_int(x);
    x += __int_as_float(__builtin_amdgcn_update_dpp(0, v, 0x128, 0xF, 0xF, true)); // row_ror:8
    return x;
}

__global__ __launch_bounds__(NT, 4)   // VGPR<=128 -> 2 blocks/CU (16 waves/CU)
void single_attn_fused3(const float* __restrict__ input,   // [B,T,D]
                        const int*   __restrict__ mask,    // [B,T]
                        const float* __restrict__ Wt,      // [D,H]
                        const float* __restrict__ Wx,      // [D,H]
                        const float* __restrict__ rate,    // [1]
                        float* __restrict__ out_v,         // [B,D]
                        float* __restrict__ out_a)         // [B,T]
{
    const int b    = blockIdx.x;
    const int tid  = threadIdx.x;
    const int lane = tid & 63;
    const int wid  = tid >> 6;
    const int seg  = tid & 15;     // 16 lanes per row; floats seg*8..seg*8+7
    const int rg   = tid >> 4;     // row group 0..31
    const float* __restrict__ inb = input + (size_t)b * Tn * Dn;
    const float4* __restrict__ in4 = (const float4*)inb;

    __shared__ float ps[Tn];          // 2 KB unnormalized weights
    __shared__ int   msk[Tn];         // 2 KB
    __shared__ float lv[Dn];
    __shared__ float qs[Hn];
    __shared__ float us[Dn];
    __shared__ float redl[NW];
    __shared__ int   ired[NW];
    __shared__ float vp[32 * 132];    // 16.9 KB v partials

    // ---- prologue: last_idx, lv, q = lv@Wt, u = Wx@q ----
    const int mv = mask[(size_t)b * Tn + tid];
    msk[tid] = mv;
    {
        int ms = mv;
        #pragma unroll
        for (int off = 32; off > 0; off >>= 1) ms += __shfl_down(ms, off, 64);
        if (lane == 0) ired[wid] = ms;
    }
    __syncthreads();
    int last_idx;
    {
        int s = 0;
        #pragma unroll
        for (int w = 0; w < NW; ++w) s += ired[w];
        last_idx = s - 1;
    }
    if (tid < Dn) lv[tid] = inb[(size_t)last_idx * Dn + tid];
    __syncthreads();
    if (tid < Hn) {
        float a0 = 0.f, a1 = 0.f;
        #pragma unroll 16
        for (int d0 = 0; d0 < Dn; d0 += 2) {
            a0 = fmaf(lv[d0],     Wt[d0 * Hn + tid],       a0);
            a1 = fmaf(lv[d0 + 1], Wt[(d0 + 1) * Hn + tid], a1);
        }
        qs[tid] = a0 + a1;
    }
    __syncthreads();
    if (tid < Dn) {
        float a0 = 0.f, a1 = 0.f;
        const float* wxr = Wx + tid * Hn;
        #pragma unroll 16
        for (int h = 0; h < Hn; h += 2) {
            a0 = fmaf(wxr[h],     qs[h],     a0);
            a1 = fmaf(wxr[h + 1], qs[h + 1], a1);
        }
        us[tid] = a0 + a1;
    }
    __syncthreads();

    const float srate = 1.f / (1.f + __expf(-rate[0]));
    const float4 u4a = ((const float4*)us)[seg * 2];
    const float4 u4b = ((const float4*)us)[seg * 2 + 1];

    // ---- fused streaming pass: dot -> p -> weighted accumulate, input read ONCE ----
    // e = relu(sig/den) in [0, ~1.45] (den >= sigmoid(0.8)*log(2.72) ~= 0.69),
    // so exp(e) <= 4.3: softmax needs no max subtraction.
    float4 v0 = make_float4(0.f, 0.f, 0.f, 0.f);
    float4 v1 = make_float4(0.f, 0.f, 0.f, 0.f);
    float  lsum = 0.f;

    #pragma unroll 8
    for (int it = 0; it < 16; ++it) {
        const int row = it * 32 + rg;              // == t
        const float4 x0 = in4[row * 32 + seg * 2];
        const float4 x1 = in4[row * 32 + seg * 2 + 1];
        float dot = x0.x * u4a.x + x0.y * u4a.y + x0.z * u4a.z + x0.w * u4a.w;
        dot = fmaf(x1.x, u4b.x, dot);
        dot = fmaf(x1.y, u4b.y, dot);
        dot = fmaf(x1.z, u4b.z, dot);
        dot = fmaf(x1.w, u4b.w, dot);
        dot = rowsum16(dot);                       // DPP reduce: no DS ops
        const float sig = 1.f / (1.f + __expf(-dot));
        const float den = srate * (__logf(2.72f + (1.f - sig)) * (float)(Tn - row));
        const float e   = fmaxf(sig / den, 0.f);
        const float p   = msk[row] ? __expf(e) : 0.f;
        v0.x = fmaf(p, x0.x, v0.x);
        v0.y = fmaf(p, x0.y, v0.y);
        v0.z = fmaf(p, x0.z, v0.z);
        v0.w = fmaf(p, x0.w, v0.w);
        v1.x = fmaf(p, x1.x, v1.x);
        v1.y = fmaf(p, x1.y, v1.y);
        v1.z = fmaf(p, x1.z, v1.z);
        v1.w = fmaf(p, x1.w, v1.w);
        if (seg == 0) { ps[row] = p; lsum += p; }
    }

    // stash v partials (16B-aligned: rg*132 + seg*8)
    {
        float* vr = vp + rg * 132 + seg * 8;
        ((float4*)vr)[0] = v0;
        ((float4*)vr)[1] = v1;
    }
    // block-reduce l (nonzero only on seg==0 lanes)
    float ls = lsum;
    #pragma unroll
    for (int off = 32; off > 0; off >>= 1) ls += __shfl_down(ls, off, 64);
    if (lane == 0) redl[wid] = ls;
    __syncthreads();   // vp + ps + redl visible

    float l = 0.f;
    #pragma unroll
    for (int w = 0; w < NW; ++w) l += redl[w];
    const float inv_l = 1.f / l;

    out_a[(size_t)b * Tn + tid] = ps[tid] * inv_l;

    if (tid < Dn) {
        float s = 0.f;
        #pragma unroll
        for (int r = 0; r < 32; ++r) s += vp[r * 132 + tid];
        out_v[(size_t)b * Dn + tid] = s * inv_l;
    }
}

extern "C" void kernel_launch(void* const* d_in, const int* in_sizes, int n_in,
                              void* d_out, int out_size, void* d_ws, size_t ws_size,
                              hipStream_t stream) {
    const float* input = (const float*)d_in[0];   // [B,T,D]
    const int*   mask  = (const int*)d_in[1];     // [B,T]
    const float* Wt    = (const float*)d_in[2];   // [D,H]
    const float* Wx    = (const float*)d_in[3];   // [D,H]
    const float* rate  = (const float*)d_in[4];   // [1]

    float* out   = (float*)d_out;
    float* out_v = out;                 // [B,D]  (return order: v, a)
    float* out_a = out + Bn * Dn;       // [B,T]

    single_attn_fused3<<<Bn, NT, 0, stream>>>(input, mask, Wt, Wx, rate, out_v, out_a);
}